// Round 2
// baseline (589.156 us; speedup 1.0000x reference)
//
#include <hip/hip_runtime.h>

#define NUM_ATOMS 40000
#define NUM_EDGES 640000
// FAN_IN = NFM = FAN_OUT = 128

// clang ext-vector types so __builtin_nontemporal_load works on 8B loads
typedef float f2v __attribute__((ext_vector_type(2)));

// ---------------------------------------------------------------------------
// Kernel R: CSR row offsets from sorted seg_i.
// rs[i] = lower_bound(seg_i, i) for i in [0, NUM_ATOMS]. rs[NUM_ATOMS] = NUM_EDGES.
// ---------------------------------------------------------------------------
__global__ void k_rowstart(const int* __restrict__ seg, int* __restrict__ rs) {
  const int i = blockIdx.x * blockDim.x + threadIdx.x;
  if (i > NUM_ATOMS) return;
  int lo = 0, hi = NUM_EDGES;
  while (lo < hi) {
    const int mid = (lo + hi) >> 1;
    if (seg[mid] < i) lo = mid + 1; else hi = mid;
  }
  rs[i] = lo;
}

// ---------------------------------------------------------------------------
// Kernel G: out[M][128] = A[M][128] @ W[128][128] (+ bias)   fp32 vector GEMM
// Used only for f = x @ W_in now (fac2out is fused into k_conv_out).
// ---------------------------------------------------------------------------
__global__ __launch_bounds__(512, 2) void k_gemm128(
    const float* __restrict__ A, const float* __restrict__ W,
    const float* __restrict__ bias, float* __restrict__ out) {
  __shared__ float AT[128 * 128];  // [k][m]
  __shared__ float Wl[128 * 128];  // [k][n]
  const int t = threadIdx.x;
  const int m0 = blockIdx.x * 128;

  {
    const float4* Wg = (const float4*)W;
    float4* Ws = (float4*)Wl;
#pragma unroll
    for (int i = 0; i < 8; ++i) Ws[t + i * 512] = Wg[t + i * 512];
  }
  {
    const int m = t & 127;
    const int kq = t >> 7;  // 0..3
    int mg = m0 + m;
    if (mg >= NUM_ATOMS) mg = NUM_ATOMS - 1;  // clamp (stores are guarded)
    const float4* ag = (const float4*)(A + (size_t)mg * 128);
#pragma unroll
    for (int i = 0; i < 8; ++i) {
      const int k4 = kq + i * 4;  // 0..31
      const float4 v = ag[k4];
      const int k = k4 * 4;
      AT[(k + 0) * 128 + m] = v.x;
      AT[(k + 1) * 128 + m] = v.y;
      AT[(k + 2) * 128 + m] = v.z;
      AT[(k + 3) * 128 + m] = v.w;
    }
  }
  __syncthreads();

  const int tx = t & 31;
  const int ty = t >> 5;

  float binit[4] = {0.f, 0.f, 0.f, 0.f};
  if (bias != nullptr) {
    const float2 bb0 = ((const float2*)bias)[tx];
    const float2 bb1 = ((const float2*)bias)[32 + tx];
    binit[0] = bb0.x; binit[1] = bb0.y; binit[2] = bb1.x; binit[3] = bb1.y;
  }
  float acc[8][4];
#pragma unroll
  for (int i = 0; i < 8; ++i)
#pragma unroll
    for (int j = 0; j < 4; ++j) acc[i][j] = binit[j];

#pragma unroll 4
  for (int k = 0; k < 128; ++k) {
    const float4 a0 = *(const float4*)&AT[k * 128 + 4 * ty];
    const float4 a1 = *(const float4*)&AT[k * 128 + 64 + 4 * ty];
    const float2 b0 = *(const float2*)&Wl[k * 128 + 2 * tx];
    const float2 b1 = *(const float2*)&Wl[k * 128 + 64 + 2 * tx];
    const float av[8] = {a0.x, a0.y, a0.z, a0.w, a1.x, a1.y, a1.z, a1.w};
    const float bv[4] = {b0.x, b0.y, b1.x, b1.y};
#pragma unroll
    for (int i = 0; i < 8; ++i)
#pragma unroll
      for (int j = 0; j < 4; ++j) acc[i][j] += av[i] * bv[j];
  }

#pragma unroll
  for (int i = 0; i < 8; ++i) {
    const int m = (i < 4) ? (4 * ty + i) : (64 + 4 * ty + (i - 4));
    const int mg = m0 + m;
    if (mg < NUM_ATOMS) {
      float2* o = (float2*)(out + (size_t)mg * 128);
      o[tx]      = make_float2(acc[i][0], acc[i][1]);
      o[32 + tx] = make_float2(acc[i][2], acc[i][3]);
    }
  }
}

// ---------------------------------------------------------------------------
// Kernel CO (R4): fused conv + fac2out.
//   tmp[a]  = sum_{e in [rs[a],rs[a+1])} w_ij[e] * f[idx_j[e]]   (in regs/LDS)
//   out[a]  = tmp[a] @ Wout + bout                                (LDS matvec)
// Persistent: grid = 256 blocks x 8 waves; Wout staged into LDS ONCE per
// block; each wave sweeps atoms a = blockIdx*8 + wv + 2048*t. This removes
// the conv buffer (20.5 MB write + 20.5 MB read) and the whole second GEMM
// dispatch. The matvec (64 KB LDS reads/atom, ~17 us/CU aggregate) hides
// under conv's HBM stalls (~56 us of w-stream).
//   - conv inner loop is IDENTICAL to the verified R2/R3 kernel.
//   - matvec lane l owns output cols {l, l+64}: LDS reads are contiguous
//     b32 (2-way bank alias = free per m136); cs[wv][k] is a broadcast.
//   - ONE __syncthreads() total (after Wout stage), before any divergent
//     per-wave loops -> no barrier-divergence hazard.
//   - zero-edge atoms: accs stay 0 -> out = bias. Correct.
// ---------------------------------------------------------------------------
__global__ __launch_bounds__(512, 2) void k_conv_out(
    const float* __restrict__ f, const float* __restrict__ w_ij,
    const int* __restrict__ idx_j, const int* __restrict__ rs,
    const float* __restrict__ Wout, const float* __restrict__ bout,
    float* __restrict__ out) {
  __shared__ float Ws[128 * 128];  // [k][n]  64 KB
  __shared__ float cs[8][128];     // per-wave conv row, 4 KB
  const int t = threadIdx.x;
  const int wv = t >> 6;  // 0..7
  const int l = t & 63;

  // stage Wout into LDS once per (persistent) block
  {
    const float4* Wg = (const float4*)Wout;
    float4* Wl4 = (float4*)Ws;
#pragma unroll
    for (int i = 0; i < 8; ++i) Wl4[t + i * 512] = Wg[t + i * 512];
  }
  __syncthreads();  // the only barrier in this kernel

  // bias for this lane's two output columns (loop-invariant)
  const float b0 = bout[l];
  const float b1 = bout[64 + l];

  for (int a = blockIdx.x * 8 + wv; a < NUM_ATOMS; a += 2048) {
    const int e0 = rs[a];
    const int e1 = rs[a + 1];
    float accx = 0.f, accy = 0.f;

    // ---------------- conv: identical to verified R2/R3 inner loop --------
    for (int base = e0; base < e1; base += 32) {
      const int n = min(32, e1 - base);  // wave-uniform
      const int nm1 = n - 1;
      int j = 0;
      if (l < n) j = __builtin_nontemporal_load(idx_j + base + l);

      f2v wr[32];
      float2 fr[32];
#pragma unroll
      for (int g = 0; g < 4; ++g) {
        if (n > g * 8) {
#pragma unroll
          for (int k = g * 8; k < g * 8 + 8; ++k) {
            const int kk = min(k, nm1);
            wr[k] = __builtin_nontemporal_load(
                (const f2v*)(w_ij + (size_t)(base + kk) * 128) + l);
          }
        }
      }
#pragma unroll
      for (int g = 0; g < 4; ++g) {
        if (n > g * 8) {
#pragma unroll
          for (int k = g * 8; k < g * 8 + 8; ++k) {
            const int kk = min(k, nm1);
            const int jk = __shfl(j, kk);
            fr[k] = ((const float2*)(f + (size_t)jk * 128))[l];
          }
        }
      }
#pragma unroll
      for (int g = 0; g < 4; ++g) {
        if (n > g * 8) {
#pragma unroll
          for (int k = g * 8; k < g * 8 + 8; ++k) {
            if (k < n) {
              accx += wr[k].x * fr[k].x;
              accy += wr[k].y * fr[k].y;
            }
          }
        }
      }
    }

    // ---------------- fused fac2out matvec --------------------------------
    // publish conv row to own wave's LDS slot (lane l holds ch 2l, 2l+1)
    ((float2*)cs[wv])[l] = make_float2(accx, accy);
    // same-wave LDS RAW: compiler inserts lgkmcnt wait; no barrier needed.

    float o0 = b0, o1 = b1;
#pragma unroll 8
    for (int k = 0; k < 128; ++k) {
      const float ck = cs[wv][k];            // broadcast (free)
      o0 += ck * Ws[k * 128 + l];            // contiguous b32, conflict-free
      o1 += ck * Ws[k * 128 + 64 + l];
    }
    out[(size_t)a * 128 + l] = o0;           // coalesced 256B per wave
    out[(size_t)a * 128 + 64 + l] = o1;
  }
}

// ---------------------------------------------------------------------------
extern "C" void kernel_launch(void* const* d_in, const int* in_sizes, int n_in,
                              void* d_out, int out_size, void* d_ws, size_t ws_size,
                              hipStream_t stream) {
  const float* x    = (const float*)d_in[0];
  const float* w_ij = (const float*)d_in[1];
  const int*   seg  = (const int*)d_in[2];
  const int*   idxj = (const int*)d_in[3];
  // d_in[4] = seg_i_sum scalar (== NUM_ATOMS, hardcoded)
  const float* Win  = (const float*)d_in[5];
  const float* Wout = (const float*)d_in[6];
  const float* bout = (const float*)d_in[7];
  float* out = (float*)d_out;

  // workspace: f (20.48 MB) | rs (40001 i32)
  float* f  = (float*)d_ws;
  int*   rs = (int*)((char*)d_ws + (size_t)NUM_ATOMS * 128 * sizeof(float));

  k_rowstart<<<(NUM_ATOMS + 1 + 255) / 256, 256, 0, stream>>>(seg, rs);
  k_gemm128<<<(NUM_ATOMS + 127) / 128, 512, 0, stream>>>(x, Win, nullptr, f);
  k_conv_out<<<256, 512, 0, stream>>>(f, w_ij, idxj, rs, Wout, bout, out);
}

// Round 3
// 518.496 us; speedup vs baseline: 1.1363x; 1.1363x over previous
//
#include <hip/hip_runtime.h>

#define NUM_ATOMS 40000
#define NUM_EDGES 640000
// FAN_IN = NFM = FAN_OUT = 128

#define GEMM_BLOCKS 313  // ceil(40000/128)
#define RS_BLOCKS 79     // ceil(40001/512)

// ---------------------------------------------------------------------------
// GEMM body (R5): out[M][128] = A[M][128] @ W[128][128] (+bias), BM=128,
// K staged in TWO 64-wide halves so LDS = 32+32 = 64 KB -> 2 blocks/CU.
// With grid=313 and 512 slots, ALL blocks resident in one round (old version:
// 128 KB LDS -> 1 block/CU -> 57 CUs ran a second serial round).
// __launch_bounds__(512,4) caps VGPR at 128 so 4 waves/SIMD materialize.
// Inner loop / LDS access pattern identical to the proven R0 kernel
// (broadcast float4 A-reads, 2-way-aliased float2 W-reads).
// ---------------------------------------------------------------------------
__device__ __forceinline__ void gemm128_body(
    const float* __restrict__ A, const float* __restrict__ W,
    const float* __restrict__ bias, float* __restrict__ out,
    float* AT, float* Wl, int bid, int t) {
  const int m0 = bid * 128;
  const int m = t & 127;
  const int kq = t >> 7;  // 0..3
  int mg = m0 + m;
  if (mg >= NUM_ATOMS) mg = NUM_ATOMS - 1;  // clamp (stores are guarded)
  const float4* ag = (const float4*)(A + (size_t)mg * 128);

  const int tx = t & 31;
  const int ty = t >> 5;

  float binit[4] = {0.f, 0.f, 0.f, 0.f};
  if (bias != nullptr) {
    const float2 bb0 = ((const float2*)bias)[tx];
    const float2 bb1 = ((const float2*)bias)[32 + tx];
    binit[0] = bb0.x; binit[1] = bb0.y; binit[2] = bb1.x; binit[3] = bb1.y;
  }
  float acc[8][4];
#pragma unroll
  for (int i = 0; i < 8; ++i)
#pragma unroll
    for (int j = 0; j < 4; ++j) acc[i][j] = binit[j];

#pragma unroll
  for (int kh = 0; kh < 2; ++kh) {
    const int k0 = kh * 64;
    // stage W rows k0..k0+63 into Wl[k][n] (contiguous copy, 8192 floats)
    {
      const float4* Wg = (const float4*)(W + (size_t)k0 * 128);
      float4* Ws4 = (float4*)Wl;
#pragma unroll
      for (int i = 0; i < 4; ++i) Ws4[t + i * 512] = Wg[t + i * 512];
    }
    // stage A cols k0..k0+63 transposed into AT[k][m]
#pragma unroll
    for (int i = 0; i < 4; ++i) {
      const int c = kq + 4 * i;           // 0..15 (float4 chunk within half)
      const float4 v = ag[(k0 >> 2) + c];
      const int k = 4 * c;
      AT[(k + 0) * 128 + m] = v.x;
      AT[(k + 1) * 128 + m] = v.y;
      AT[(k + 2) * 128 + m] = v.z;
      AT[(k + 3) * 128 + m] = v.w;
    }
    __syncthreads();

#pragma unroll 4
    for (int k = 0; k < 64; ++k) {
      const float4 a0 = *(const float4*)&AT[k * 128 + 4 * ty];
      const float4 a1 = *(const float4*)&AT[k * 128 + 64 + 4 * ty];
      const float2 b0 = *(const float2*)&Wl[k * 128 + 2 * tx];
      const float2 b1 = *(const float2*)&Wl[k * 128 + 64 + 2 * tx];
      const float av[8] = {a0.x, a0.y, a0.z, a0.w, a1.x, a1.y, a1.z, a1.w};
      const float bv[4] = {b0.x, b0.y, b1.x, b1.y};
#pragma unroll
      for (int i = 0; i < 8; ++i)
#pragma unroll
        for (int j = 0; j < 4; ++j) acc[i][j] += av[i] * bv[j];
    }
    __syncthreads();  // protect LDS before restaging next half
  }

#pragma unroll
  for (int i = 0; i < 8; ++i) {
    const int mm = (i < 4) ? (4 * ty + i) : (64 + 4 * ty + (i - 4));
    const int mg2 = m0 + mm;
    if (mg2 < NUM_ATOMS) {
      float2* o = (float2*)(out + (size_t)mg2 * 128);
      o[tx]      = make_float2(acc[i][0], acc[i][1]);
      o[32 + tx] = make_float2(acc[i][2], acc[i][3]);
    }
  }
}

// ---------------------------------------------------------------------------
// Kernel PRE: blocks [0,313) = gemm1 (f = x @ W_in, no bias);
//             blocks [313,392) = CSR rowstart (independent work, merged to
//             save one launch gap; both must precede conv).
// ---------------------------------------------------------------------------
__global__ __launch_bounds__(512, 4) void k_pre(
    const float* __restrict__ A, const float* __restrict__ W,
    float* __restrict__ out,
    const int* __restrict__ seg, int* __restrict__ rs) {
  __shared__ float AT[64 * 128];  // 32 KB
  __shared__ float Wl[64 * 128];  // 32 KB
  const int t = threadIdx.x;
  if (blockIdx.x >= GEMM_BLOCKS) {
    // rowstart path: rs[i] = lower_bound(seg, i)
    const int i = (blockIdx.x - GEMM_BLOCKS) * 512 + t;
    if (i <= NUM_ATOMS) {
      int lo = 0, hi = NUM_EDGES;
      while (lo < hi) {
        const int mid = (lo + hi) >> 1;
        if (seg[mid] < i) lo = mid + 1; else hi = mid;
      }
      rs[i] = lo;
    }
    return;  // early return before any barrier: barriers are per-block, safe
  }
  gemm128_body(A, W, nullptr, out, AT, Wl, blockIdx.x, t);
}

// ---------------------------------------------------------------------------
// Kernel OUT: out = conv @ W_out + b_out (same two-half GEMM)
// ---------------------------------------------------------------------------
__global__ __launch_bounds__(512, 4) void k_out(
    const float* __restrict__ A, const float* __restrict__ W,
    const float* __restrict__ bias, float* __restrict__ out) {
  __shared__ float AT[64 * 128];
  __shared__ float Wl[64 * 128];
  gemm128_body(A, W, bias, out, AT, Wl, blockIdx.x, threadIdx.x);
}

// ---------------------------------------------------------------------------
// Kernel C: conv[a] = sum_{e in [rs[a],rs[a+1])} w_ij[e] * f[idx_j[e]]
// EXACT R0 kernel (best measured: 545.2 us total). One wave per atom; per
// <=32-edge chunk preload all w/f rows into registers (up to 16 KB in flight
// per wave), then one wait + FMA burst. Lane l owns channels 2l, 2l+1.
// ---------------------------------------------------------------------------
__global__ __launch_bounds__(256) void k_conv(
    const float* __restrict__ f, const float* __restrict__ w_ij,
    const int* __restrict__ idx_j, const int* __restrict__ rs,
    float* __restrict__ conv) {
  const int wv = threadIdx.x >> 6;
  const int l = threadIdx.x & 63;
  const int a = blockIdx.x * 4 + wv;  // 40000 = 10000 * 4, always in range

  const int e0 = rs[a];
  const int e1 = rs[a + 1];
  float accx = 0.f, accy = 0.f;

  for (int base = e0; base < e1; base += 32) {
    const int n = min(32, e1 - base);  // wave-uniform
    const int nm1 = n - 1;
    int j = 0;
    if (l < n) j = idx_j[base + l];

    float2 wr[32], fr[32];
#pragma unroll
    for (int g = 0; g < 4; ++g) {
      if (n > g * 8) {
#pragma unroll
        for (int k = g * 8; k < g * 8 + 8; ++k) {
          const int kk = min(k, nm1);
          wr[k] = ((const float2*)(w_ij + (size_t)(base + kk) * 128))[l];
        }
      }
    }
#pragma unroll
    for (int g = 0; g < 4; ++g) {
      if (n > g * 8) {
#pragma unroll
        for (int k = g * 8; k < g * 8 + 8; ++k) {
          const int kk = min(k, nm1);
          const int jk = __shfl(j, kk);
          fr[k] = ((const float2*)(f + (size_t)jk * 128))[l];
        }
      }
    }
#pragma unroll
    for (int g = 0; g < 4; ++g) {
      if (n > g * 8) {
#pragma unroll
        for (int k = g * 8; k < g * 8 + 8; ++k) {
          if (k < n) {
            accx += wr[k].x * fr[k].x;
            accy += wr[k].y * fr[k].y;
          }
        }
      }
    }
  }
  ((float2*)(conv + (size_t)a * 128))[l] = make_float2(accx, accy);
}

// ---------------------------------------------------------------------------
extern "C" void kernel_launch(void* const* d_in, const int* in_sizes, int n_in,
                              void* d_out, int out_size, void* d_ws, size_t ws_size,
                              hipStream_t stream) {
  const float* x    = (const float*)d_in[0];
  const float* w_ij = (const float*)d_in[1];
  const int*   seg  = (const int*)d_in[2];
  const int*   idxj = (const int*)d_in[3];
  // d_in[4] = seg_i_sum scalar (== NUM_ATOMS, hardcoded)
  const float* Win  = (const float*)d_in[5];
  const float* Wout = (const float*)d_in[6];
  const float* bout = (const float*)d_in[7];
  float* out = (float*)d_out;

  // workspace: f (20.48 MB) | conv (20.48 MB) | rs (40001 i32)
  float* f    = (float*)d_ws;
  float* conv = (float*)((char*)d_ws + (size_t)NUM_ATOMS * 128 * sizeof(float));
  int*   rs   = (int*)((char*)d_ws + 2 * (size_t)NUM_ATOMS * 128 * sizeof(float));

  k_pre<<<GEMM_BLOCKS + RS_BLOCKS, 512, 0, stream>>>(x, Win, f, seg, rs);
  k_conv<<<NUM_ATOMS / 4, 256, 0, stream>>>(f, w_ij, idxj, rs, conv);
  k_out<<<GEMM_BLOCKS, 512, 0, stream>>>(conv, Wout, bout, out);
}